// Round 6
// baseline (544.722 us; speedup 1.0000x reference)
//
#include <hip/hip_runtime.h>

#define HW 65536

typedef __bf16 bf16x8 __attribute__((ext_vector_type(8)));
typedef float f32x16 __attribute__((ext_vector_type(16)));

__device__ inline unsigned short f2bf(float x) {
    union { float f; unsigned u; } v; v.f = x;
    unsigned r = v.u + 0x7FFF + ((v.u >> 16) & 1);   // RNE
    return (unsigned short)(r >> 16);
}
__device__ inline float bfhi2f(unsigned u) {
    union { unsigned u; float f; } v; v.u = u & 0xffff0000u; return v.f;
}
__device__ inline float bflo2f(unsigned u) {
    union { unsigned u; float f; } v; v.u = u << 16; return v.f;
}

union FragU { uint4 u; bf16x8 v; };
__device__ inline bf16x8 ld_frag(const uint4* p) { FragU t; t.u = *p; return t.v; }

// ---------------------------------------------------------------------------
// Weight pre-transform:
//  layers 0..5 (conv3x3): w[oc][ic][tap] -> [tap][ig][oc][j]  (ic = ig*8+j)
//  layer  6   (kg_w5)   : w5[q][ic]     -> [kk][ig][cc][j]    (q = kk*64+cc)
//  layer  7   (tensor_w): flat [oc][k] bf16 (unchanged)
// Layouts make per-lane 16B A-fragment loads from GLOBAL fully coalesced.
// ---------------------------------------------------------------------------
__global__ __launch_bounds__(256) void k_wprep(
    const float* __restrict__ w0, const float* __restrict__ w1,
    const float* __restrict__ w2, const float* __restrict__ w3,
    const float* __restrict__ w4, const float* __restrict__ w5,
    const float* __restrict__ w5c, const float* __restrict__ tw,
    unsigned short* __restrict__ wT)
{
    int y = blockIdx.y;
    unsigned short* o = wT + (size_t)y * 36864;
    if (y < 6) {
        const float* ws_[6] = {w0, w1, w2, w3, w4, w5};
        const float* w = ws_[y];
        for (int e = blockIdx.x * 256 + threadIdx.x; e < 36864; e += gridDim.x * 256) {
            int j = e & 7, oc = (e >> 3) & 63, ig = (e >> 9) & 7, tap = e >> 12;
            o[e] = f2bf(w[(oc * 64 + ig * 8 + j) * 9 + tap]);
        }
    } else if (y == 6) {
        for (int e = blockIdx.x * 256 + threadIdx.x; e < 36864; e += gridDim.x * 256) {
            int j = e & 7, cc = (e >> 3) & 63, ig = (e >> 9) & 7, kk = e >> 12;
            o[e] = f2bf(w5c[(kk * 64 + cc) * 64 + ig * 8 + j]);
        }
    } else {
        for (int e = blockIdx.x * 256 + threadIdx.x; e < 8192; e += gridDim.x * 256)
            o[e] = f2bf(tw[e]);
    }
}

// ---------------------------------------------------------------------------
// k_tr: NCHW fp32 -> NHWC bf16 for img and guidance.
// ---------------------------------------------------------------------------
__global__ __launch_bounds__(256) void k_tr(
    const float* __restrict__ img, const float* __restrict__ gd,
    unsigned short* __restrict__ imgT, unsigned short* __restrict__ gdT)
{
    __shared__ float sT[64 * 66];
    int tid = threadIdx.x;
    int z = blockIdx.y;
    int b = z & 1;
    const float* src = (z >> 1) ? gd : img;
    unsigned short* dst = (z >> 1) ? gdT : imgT;
    int px0 = blockIdx.x * 64;
    size_t sbase = (size_t)b * 64 * HW + px0;

#pragma unroll
    for (int i = 0; i < 4; ++i) {
        int e = i * 256 + tid;
        int ic = e >> 4, seg = e & 15;
        float4 v = *(const float4*)(src + sbase + (size_t)ic * HW + seg * 4);
        float* p = &sT[ic * 66 + seg * 4];
        ((float2*)p)[0] = make_float2(v.x, v.y);
        ((float2*)p)[1] = make_float2(v.z, v.w);
    }
    __syncthreads();

    size_t dbase = (size_t)b * HW * 64 + (size_t)px0 * 64;
#pragma unroll
    for (int k = 0; k < 2; ++k) {
        int idx = k * 256 + tid;
        int px = idx >> 3, u = idx & 7;
        union { uint4 q; unsigned short h[8]; } o;
#pragma unroll
        for (int j = 0; j < 8; ++j)
            o.h[j] = f2bf(sT[(u * 8 + j) * 66 + px]);
        *(uint4*)(dst + dbase + (size_t)px * 64 + u * 8) = o.q;
    }
}

// ---------------------------------------------------------------------------
// k_fusem: 1x1 (2C->C) + PReLU (unchanged from round 5).
// ---------------------------------------------------------------------------
__global__ __launch_bounds__(256, 2) void k_fusem(
    const unsigned short* __restrict__ imgT, const unsigned short* __restrict__ gdT,
    const unsigned short* __restrict__ wTf, const float* __restrict__ bias,
    const float* __restrict__ a, unsigned short* __restrict__ out)
{
    __shared__ __align__(16) char smem[53504];
    uint4* sX = (uint4*)smem;
    uint4* sW = (uint4*)(smem + 36864);
    float* sB = (float*)(smem + 53248);
    unsigned short* sT16 = (unsigned short*)smem;

    int tid = threadIdx.x;
    int wv = tid >> 6, lane = tid & 63;
    int half = lane >> 5, l31 = lane & 31;
    int b = blockIdx.z;
    int y0 = blockIdx.y * 8, x0 = blockIdx.x * 32;
    size_t zbase = (size_t)b * HW * 64;

    for (int ch = tid; ch < 1024; ch += 256) {
        int kg = ch >> 6, oc = ch & 63;
        sW[ch] = ((const uint4*)wTf)[oc * 16 + kg];
    }
    if (tid < 64) sB[tid] = bias[tid];

    f32x16 acc[2][2];
#pragma unroll
    for (int i = 0; i < 2; ++i)
#pragma unroll
        for (int j = 0; j < 2; ++j)
#pragma unroll
            for (int r = 0; r < 16; ++r) acc[i][j][r] = 0.f;

    for (int h = 0; h < 2; ++h) {
        __syncthreads();
        const unsigned short* src = h ? gdT : imgT;
#pragma unroll
        for (int i = 0; i < 8; ++i) {
            int e = i * 256 + tid;
            int px = e >> 3, ig = e & 7;
            int gy = y0 + (px >> 5), gx = x0 + (px & 31);
            uint4 v = *(const uint4*)(src + zbase + ((size_t)(gy * 256 + gx)) * 64 + ig * 8);
            sX[px * 9 + ig] = v;
        }
        __syncthreads();
#pragma unroll
        for (int c = 0; c < 4; ++c) {
            int ig = c * 2 + half;
            int kg = h * 8 + ig;
            bf16x8 a0 = ld_frag(&sW[kg * 64 + l31]);
            bf16x8 a1 = ld_frag(&sW[kg * 64 + 32 + l31]);
            int p0 = wv * 64 + l31;
            bf16x8 b0 = ld_frag(&sX[p0 * 9 + ig]);
            bf16x8 b1 = ld_frag(&sX[(p0 + 32) * 9 + ig]);
            acc[0][0] = __builtin_amdgcn_mfma_f32_32x32x16_bf16(a0, b0, acc[0][0], 0, 0, 0);
            acc[0][1] = __builtin_amdgcn_mfma_f32_32x32x16_bf16(a0, b1, acc[0][1], 0, 0, 0);
            acc[1][0] = __builtin_amdgcn_mfma_f32_32x32x16_bf16(a1, b0, acc[1][0], 0, 0, 0);
            acc[1][1] = __builtin_amdgcn_mfma_f32_32x32x16_bf16(a1, b1, acc[1][1], 0, 0, 0);
        }
    }

    float slope = a[0];
    __syncthreads();
#pragma unroll
    for (int ot = 0; ot < 2; ++ot)
#pragma unroll
        for (int pt = 0; pt < 2; ++pt) {
            int px = wv * 64 + pt * 32 + l31;
#pragma unroll
            for (int q2 = 0; q2 < 4; ++q2) {
                unsigned short hw[4];
#pragma unroll
                for (int j = 0; j < 4; ++j) {
                    int r = (q2 << 2) | j;
                    int oc = ot * 32 + j + 8 * q2 + 4 * half;
                    float v = acc[ot][pt][r] + sB[oc];
                    v = (v >= 0.f) ? v : slope * v;
                    hw[j] = f2bf(v);
                }
                int unit = ot * 4 + q2;
                int up = unit ^ (px & 7);
                uint2* p = (uint2*)&sT16[px * 64 + up * 8 + half * 4];
                *p = make_uint2((unsigned)hw[0] | ((unsigned)hw[1] << 16),
                                (unsigned)hw[2] | ((unsigned)hw[3] << 16));
            }
        }
    __syncthreads();
#pragma unroll
    for (int k = 0; k < 8; ++k) {
        int col = tid >> 3, u = tid & 7;
        int px = k * 32 + col;
        uint4 v = *(uint4*)&sT16[px * 64 + (u ^ (px & 7)) * 8];
        *(uint4*)(out + zbase + ((size_t)((y0 + k) * 256 + x0 + col)) * 64 + u * 8) = v;
    }
}

// ---------------------------------------------------------------------------
// k_conv3m v2: 3x3 conv C=64->64 pad 1, bf16 MFMA, NHWC bf16 in.
// Single stage phase: full 64-ch halo in LDS (one barrier); MFMA A-operands
// streamed directly from global (coalesced, L1-shared across waves).
// MODE 0: PReLU, NHWC bf16 out.  MODE 2: + fp32 residual, NCHW fp32 out.
// ---------------------------------------------------------------------------
template<int MODE>
__global__ __launch_bounds__(256, 2) void k_conv3m(
    const unsigned short* __restrict__ in, const unsigned short* __restrict__ wT,
    const float* __restrict__ bias, const float* __restrict__ a,
    const float* __restrict__ res, void* __restrict__ outv)
{
    __shared__ __align__(16) char smem[46912];
    uint4* sX = (uint4*)smem;                     // 2916 uint4: [cell][ig 0..7 +pad]
    float* sB = (float*)(smem + 46656);
    unsigned short* sT16 = (unsigned short*)smem; // epilogue overlay (MODE 0)

    int tid = threadIdx.x;
    int wv = tid >> 6, lane = tid & 63;
    int half = lane >> 5, l31 = lane & 31;
    int b = blockIdx.z;
    int y0 = blockIdx.y * 16, x0 = blockIdx.x * 16;
    const size_t zbase = (size_t)b * HW * 64;

    if (tid < 64) sB[tid] = bias[tid];

    // stage full halo: 18x18 cells x 8 uint4 (64 ch)
    for (int e = tid; e < 2592; e += 256) {
        int cell = e >> 3, ig = e & 7;
        int r = cell / 18, c = cell - r * 18;
        int gy = y0 + r - 1, gx = x0 + c - 1;
        uint4 v = make_uint4(0, 0, 0, 0);
        if (gy >= 0 && gy < 256 && gx >= 0 && gx < 256)
            v = *(const uint4*)(in + zbase + ((size_t)(gy * 256 + gx)) * 64 + ig * 8);
        sX[cell * 9 + ig] = v;
    }
    __syncthreads();

    f32x16 acc[2][2];
#pragma unroll
    for (int i = 0; i < 2; ++i)
#pragma unroll
        for (int j = 0; j < 2; ++j)
#pragma unroll
            for (int r = 0; r < 16; ++r) acc[i][j][r] = 0.f;

    const uint4* wq = (const uint4*)wT;
#pragma unroll
    for (int tap = 0; tap < 9; ++tap) {
        int dy = tap / 3, dx = tap % 3;
#pragma unroll
        for (int c = 0; c < 4; ++c) {
            int ig = c * 2 + half;
            // A from global (coalesced per-lane 16B, L1-shared)
            bf16x8 a0 = ld_frag(&wq[(tap * 8 + ig) * 64 + l31]);
            bf16x8 a1 = ld_frag(&wq[(tap * 8 + ig) * 64 + 32 + l31]);
            int p0 = wv * 64 + l31;
            int p1 = p0 + 32;
            int u0 = ((((p0 >> 4) + dy) * 18) + (p0 & 15) + dx) * 9 + ig;
            int u1 = ((((p1 >> 4) + dy) * 18) + (p1 & 15) + dx) * 9 + ig;
            bf16x8 b0 = ld_frag(&sX[u0]);
            bf16x8 b1 = ld_frag(&sX[u1]);
            acc[0][0] = __builtin_amdgcn_mfma_f32_32x32x16_bf16(a0, b0, acc[0][0], 0, 0, 0);
            acc[0][1] = __builtin_amdgcn_mfma_f32_32x32x16_bf16(a0, b1, acc[0][1], 0, 0, 0);
            acc[1][0] = __builtin_amdgcn_mfma_f32_32x32x16_bf16(a1, b0, acc[1][0], 0, 0, 0);
            acc[1][1] = __builtin_amdgcn_mfma_f32_32x32x16_bf16(a1, b1, acc[1][1], 0, 0, 0);
        }
    }

    if (MODE == 0) {
        float slope = a[0];
        __syncthreads();
#pragma unroll
        for (int ot = 0; ot < 2; ++ot)
#pragma unroll
            for (int pt = 0; pt < 2; ++pt) {
                int px = wv * 64 + pt * 32 + l31;
#pragma unroll
                for (int q2 = 0; q2 < 4; ++q2) {
                    unsigned short hw[4];
#pragma unroll
                    for (int j = 0; j < 4; ++j) {
                        int r = (q2 << 2) | j;
                        int oc = ot * 32 + j + 8 * q2 + 4 * half;
                        float v = acc[ot][pt][r] + sB[oc];
                        v = (v >= 0.f) ? v : slope * v;
                        hw[j] = f2bf(v);
                    }
                    int unit = ot * 4 + q2;
                    int up = unit ^ (px & 7);
                    uint2* p = (uint2*)&sT16[px * 64 + up * 8 + half * 4];
                    *p = make_uint2((unsigned)hw[0] | ((unsigned)hw[1] << 16),
                                    (unsigned)hw[2] | ((unsigned)hw[3] << 16));
                }
            }
        __syncthreads();
        unsigned short* outT = (unsigned short*)outv;
#pragma unroll
        for (int k = 0; k < 8; ++k) {
            int idx = k * 256 + tid;
            int row = idx >> 7, rem = idx & 127;
            int col = rem >> 3, u = rem & 7;
            int px = row * 16 + col;
            uint4 v = *(uint4*)&sT16[px * 64 + (u ^ (px & 7)) * 8];
            *(uint4*)(outT + zbase + ((size_t)((y0 + row) * 256 + x0 + col)) * 64 + u * 8) = v;
        }
    } else {
        float* outF = (float*)outv;
#pragma unroll
        for (int ot = 0; ot < 2; ++ot)
#pragma unroll
            for (int pt = 0; pt < 2; ++pt) {
                int p = wv * 64 + pt * 32 + l31;
                int y = y0 + (p >> 4), x = x0 + (p & 15);
                size_t pbase = (size_t)b * 64 * HW + (size_t)y * 256 + x;
#pragma unroll
                for (int r = 0; r < 16; ++r) {
                    int oc = ot * 32 + (r & 3) + 8 * (r >> 2) + 4 * half;
                    float v = acc[ot][pt][r] + sB[oc];
                    v += res[pbase + (size_t)oc * HW];
                    outF[pbase + (size_t)oc * HW] = v;
                }
            }
    }
}

// ---------------------------------------------------------------------------
// k_jbfm v2: fused kg_w5 (C->576) + dynamic-kernel combine.
// A-frags from global (layout [kk][ig][cc][8]); patch staging double-buffered:
// loads for kk+1 issue before compute(kk), LDS writes after -> latency hidden.
// One barrier per kk.
// ---------------------------------------------------------------------------
__global__ __launch_bounds__(256, 2) void k_jbfm(
    const unsigned short* __restrict__ y4, const float* __restrict__ img,
    const unsigned short* __restrict__ w5T, const float* __restrict__ b5,
    unsigned short* __restrict__ out)
{
    __shared__ __align__(16) char smem[62208];
    uint4* sY = (uint4*)smem;                    // 2304 uint4 [px][ig 0..8(pad)]
    unsigned* sPd = (unsigned*)(smem + 36864);   // 2 x 2880 u32 patch buffers
    float* sB5 = (float*)(smem + 59904);         // 576 f32
    unsigned short* sT16 = (unsigned short*)smem;

    int tid = threadIdx.x;
    int wv = tid >> 6, lane = tid & 63;
    int half = lane >> 5, l31 = lane & 31;
    int b = blockIdx.z;
    int y0 = blockIdx.y * 8, x0 = blockIdx.x * 32;
    size_t zbase = (size_t)b * HW * 64;
    size_t ibase = (size_t)b * 64 * HW;

#pragma unroll
    for (int i = 0; i < 8; ++i) {
        int e = i * 256 + tid;
        int px = e >> 3, ig = e & 7;
        int gy = y0 + (px >> 5), gx = x0 + (px & 31);
        sY[px * 9 + ig] = *(const uint4*)(y4 + zbase + ((size_t)(gy * 256 + gx)) * 64 + ig * 8);
    }
    for (int e = tid; e < 576; e += 256) sB5[e] = b5[e];

    // initial patch stage for kk=0
    {
        const int chlo = 0;
#pragma unroll
        for (int i = 0; i < 3; ++i) {
            int e = i * 256 + tid;
            if (e < 720) {
                int ch = e / 90, rem = e - ch * 90;
                int rp = rem / 10, seg = rem - rp * 10;
                int gy = y0 + rp - 1;
                int gxb = x0 - 4 + seg * 4;
                bool xok = (gxb >= 0 && gxb < 256);
                float4 fa = make_float4(0, 0, 0, 0), fb = make_float4(0, 0, 0, 0);
                const float* rowp = img + ibase + (size_t)(chlo + ch) * HW + gxb;
                if (xok && gy >= 0 && gy < 256)         fa = *(const float4*)(rowp + (size_t)gy * 256);
                if (xok && gy + 1 >= 0 && gy + 1 < 256) fb = *(const float4*)(rowp + (size_t)(gy + 1) * 256);
                uint4 pk;
                pk.x = (unsigned)f2bf(fa.x) | ((unsigned)f2bf(fb.x) << 16);
                pk.y = (unsigned)f2bf(fa.y) | ((unsigned)f2bf(fb.y) << 16);
                pk.z = (unsigned)f2bf(fa.z) | ((unsigned)f2bf(fb.z) << 16);
                pk.w = (unsigned)f2bf(fa.w) | ((unsigned)f2bf(fb.w) << 16);
                *(uint4*)&sPd[ch * 360 + rp * 40 + seg * 4] = pk;
            }
        }
    }
    __syncthreads();

    float jb[2][2][16];
#pragma unroll
    for (int i = 0; i < 2; ++i)
#pragma unroll
        for (int j = 0; j < 2; ++j)
#pragma unroll
            for (int r = 0; r < 16; ++r) jb[i][j][r] = 0.f;

    const uint4* w5q = (const uint4*)w5T;

#pragma unroll
    for (int kk = 0; kk < 9; ++kk) {
        const int chlo = (kk * 64) / 9;
        unsigned* cur = sPd + (kk & 1) * 2880;
        unsigned* nxt = sPd + ((kk + 1) & 1) * 2880;

        // --- prefetch loads for kk+1 (registers) ---
        float4 fa[3], fb[3];
        int doff[3];
        if (kk < 8) {
            const int chlo2 = ((kk + 1) * 64) / 9;
#pragma unroll
            for (int i = 0; i < 3; ++i) {
                int e = i * 256 + tid;
                fa[i] = make_float4(0, 0, 0, 0);
                fb[i] = make_float4(0, 0, 0, 0);
                doff[i] = -1;
                if (e < 720) {
                    int ch = e / 90, rem = e - ch * 90;
                    int rp = rem / 10, seg = rem - rp * 10;
                    int gy = y0 + rp - 1;
                    int gxb = x0 - 4 + seg * 4;
                    bool xok = (gxb >= 0 && gxb < 256);
                    const float* rowp = img + ibase + (size_t)(chlo2 + ch) * HW + gxb;
                    if (xok && gy >= 0 && gy < 256)         fa[i] = *(const float4*)(rowp + (size_t)gy * 256);
                    if (xok && gy + 1 >= 0 && gy + 1 < 256) fb[i] = *(const float4*)(rowp + (size_t)(gy + 1) * 256);
                    doff[i] = ch * 360 + rp * 40 + seg * 4;
                }
            }
        }

        // --- bias-init accumulators ---
        f32x16 acc[2][2];
#pragma unroll
        for (int ot = 0; ot < 2; ++ot)
#pragma unroll
            for (int r = 0; r < 16; ++r) {
                int cc0 = ot * 32 + (r & 3) + 8 * (r >> 2);
                float bv = sB5[kk * 64 + cc0 + 4 * half];
                acc[ot][0][r] = bv;
                acc[ot][1][r] = bv;
            }

        // --- MFMA: bi = W5_slice @ y4 ---
#pragma unroll
        for (int c = 0; c < 4; ++c) {
            int ig = c * 2 + half;
            bf16x8 a0 = ld_frag(&w5q[(kk * 8 + ig) * 64 + l31]);
            bf16x8 a1 = ld_frag(&w5q[(kk * 8 + ig) * 64 + 32 + l31]);
            int p0 = wv * 64 + l31;
            bf16x8 b0 = ld_frag(&sY[p0 * 9 + ig]);
            bf16x8 b1 = ld_frag(&sY[(p0 + 32) * 9 + ig]);
            acc[0][0] = __builtin_amdgcn_mfma_f32_32x32x16_bf16(a0, b0, acc[0][0], 0, 0, 0);
            acc[0][1] = __builtin_amdgcn_mfma_f32_32x32x16_bf16(a0, b1, acc[0][1], 0, 0, 0);
            acc[1][0] = __builtin_amdgcn_mfma_f32_32x32x16_bf16(a1, b0, acc[1][0], 0, 0, 0);
            acc[1][1] = __builtin_amdgcn_mfma_f32_32x32x16_bf16(a1, b1, acc[1][1], 0, 0, 0);
        }

        // --- combine: one packed b32 read serves both pt pixels ---
        {
            const unsigned* basep = cur + wv * 80 + l31 + 3;
#pragma unroll
            for (int ot = 0; ot < 2; ++ot)
#pragma unroll
                for (int r = 0; r < 16; ++r) {
                    const int cc0 = ot * 32 + (r & 3) + 8 * (r >> 2);
                    const int q0 = kk * 64 + cc0, q1 = q0 + 4;
                    const int o0 = (q0 / 9 - chlo) * 360 + (q0 % 9 / 3) * 40 + q0 % 9 % 3;
                    const int o1 = (q1 / 9 - chlo) * 360 + (q1 % 9 / 3) * 40 + q1 % 9 % 3;
                    unsigned pv = basep[half ? o1 : o0];
                    jb[ot][0][r] = fmaf(acc[ot][0][r], bflo2f(pv), jb[ot][0][r]);
                    jb[ot][1][r] = fmaf(acc[ot][1][r], bfhi2f(pv), jb[ot][1][r]);
                }
        }

        // --- write prefetched patches for kk+1 ---
        if (kk < 8) {
#pragma unroll
            for (int i = 0; i < 3; ++i)
                if (doff[i] >= 0) {
                    uint4 pk;
                    pk.x = (unsigned)f2bf(fa[i].x) | ((unsigned)f2bf(fb[i].x) << 16);
                    pk.y = (unsigned)f2bf(fa[i].y) | ((unsigned)f2bf(fb[i].y) << 16);
                    pk.z = (unsigned)f2bf(fa[i].z) | ((unsigned)f2bf(fb[i].z) << 16);
                    pk.w = (unsigned)f2bf(fa[i].w) | ((unsigned)f2bf(fb[i].w) << 16);
                    *(uint4*)&nxt[doff[i]] = pk;
                }
        }
        __syncthreads();
    }

    // epilogue: NHWC bf16 out via swizzled LDS transpose
#pragma unroll
    for (int ot = 0; ot < 2; ++ot)
#pragma unroll
        for (int pt = 0; pt < 2; ++pt) {
            int px = wv * 64 + pt * 32 + l31;
#pragma unroll
            for (int q2 = 0; q2 < 4; ++q2) {
                unsigned short hw[4];
#pragma unroll
                for (int j = 0; j < 4; ++j) {
                    int r = (q2 << 2) | j;
                    hw[j] = f2bf(jb[ot][pt][r]);
                }
                int unit = ot * 4 + q2;
                int up = unit ^ (px & 7);
                uint2* p = (uint2*)&sT16[px * 64 + up * 8 + half * 4];
                *p = make_uint2((unsigned)hw[0] | ((unsigned)hw[1] << 16),
                                (unsigned)hw[2] | ((unsigned)hw[3] << 16));
            }
        }
    __syncthreads();
#pragma unroll
    for (int k = 0; k < 8; ++k) {
        int col = tid >> 3, u = tid & 7;
        int px = k * 32 + col;
        uint4 v = *(uint4*)&sT16[px * 64 + (u ^ (px & 7)) * 8];
        *(uint4*)(out + zbase + ((size_t)((y0 + k) * 256 + x0 + col)) * 64 + u * 8) = v;
    }
}

// ---------------------------------------------------------------------------
extern "C" void kernel_launch(void* const* d_in, const int* in_sizes, int n_in,
                              void* d_out, int out_size, void* d_ws, size_t ws_size,
                              hipStream_t stream) {
    const float* img  = (const float*)d_in[0];
    const float* gd   = (const float*)d_in[1];
    const float* tw   = (const float*)d_in[2];
    const float* tb   = (const float*)d_in[3];
    const float* ajbf = (const float*)d_in[4];
    const float* kw1  = (const float*)d_in[5];
    const float* kb1  = (const float*)d_in[6];
    const float* kw2  = (const float*)d_in[7];
    const float* kb2  = (const float*)d_in[8];
    const float* kw3  = (const float*)d_in[9];
    const float* kb3  = (const float*)d_in[10];
    const float* kw4  = (const float*)d_in[11];
    const float* kb4  = (const float*)d_in[12];
    const float* kw5  = (const float*)d_in[13];
    const float* kb5  = (const float*)d_in[14];
    const float* akg  = (const float*)d_in[15];
    const float* jw1  = (const float*)d_in[16];
    const float* jb1  = (const float*)d_in[17];
    const float* jw2  = (const float*)d_in[18];
    const float* jb2  = (const float*)d_in[19];
    float* out  = (float*)d_out;

    const size_t TEN = (size_t)2 * HW * 64;
    unsigned short* bufA = (unsigned short*)d_ws;
    unsigned short* imgT = bufA + TEN;
    unsigned short* gdT  = imgT + TEN;
    unsigned short* wT   = gdT + TEN;
    unsigned short* bufB = (unsigned short*)d_out;

    dim3 g3(16, 16, 2);
    dim3 gw(8, 32, 2);

    k_tr<<<dim3(1024, 4), 256, 0, stream>>>(img, gd, imgT, gdT);
    k_wprep<<<dim3(4, 8), 256, 0, stream>>>(kw1, kw2, kw3, kw4, jw1, jw2, kw5, tw, wT);

    k_fusem<<<gw, 256, 0, stream>>>(imgT, gdT, wT + (size_t)7 * 36864, tb, ajbf, bufA);

    k_conv3m<0><<<g3, 256, 0, stream>>>(bufA, wT + (size_t)0 * 36864, kb1, akg, nullptr, bufB);
    k_conv3m<0><<<g3, 256, 0, stream>>>(bufB, wT + (size_t)1 * 36864, kb2, akg, nullptr, bufA);
    k_conv3m<0><<<g3, 256, 0, stream>>>(bufA, wT + (size_t)2 * 36864, kb3, akg, nullptr, bufB);
    k_conv3m<0><<<g3, 256, 0, stream>>>(bufB, wT + (size_t)3 * 36864, kb4, akg, nullptr, bufA);

    k_jbfm<<<gw, 256, 0, stream>>>(bufA, img, wT + (size_t)6 * 36864, kb5, bufB);

    k_conv3m<0><<<g3, 256, 0, stream>>>(bufB, wT + (size_t)4 * 36864, jb1, ajbf, nullptr, bufA);
    k_conv3m<2><<<g3, 256, 0, stream>>>(bufA, wT + (size_t)5 * 36864, jb2, ajbf, img, out);
}

// Round 7
// 449.441 us; speedup vs baseline: 1.2120x; 1.2120x over previous
//
#include <hip/hip_runtime.h>

#define HW 65536

typedef __bf16 bf16x8 __attribute__((ext_vector_type(8)));
typedef float f32x16 __attribute__((ext_vector_type(16)));

__device__ inline unsigned short f2bf(float x) {
    union { float f; unsigned u; } v; v.f = x;
    unsigned r = v.u + 0x7FFF + ((v.u >> 16) & 1);   // RNE
    return (unsigned short)(r >> 16);
}
__device__ inline float bfhi2f(unsigned u) {
    union { unsigned u; float f; } v; v.u = u & 0xffff0000u; return v.f;
}
__device__ inline float bflo2f(unsigned u) {
    union { unsigned u; float f; } v; v.u = u << 16; return v.f;
}

union FragU { uint4 u; bf16x8 v; };
__device__ inline bf16x8 ld_frag(const uint4* p) { FragU t; t.u = *p; return t.v; }

// ---------------------------------------------------------------------------
// Weight pre-transform:
//  layers 0..5 (conv3x3): w[oc][ic][tap] -> [tap][ig][oc][j]  (ic = ig*8+j)
//    -> per-lane 16B A-frag loads from GLOBAL are fully coalesced.
//  layer  6   (kg_w5)   : flat [q][ic] bf16 (round-5 jbfm layout)
//  layer  7   (tensor_w): flat [oc][k] bf16
// ---------------------------------------------------------------------------
__global__ __launch_bounds__(256) void k_wprep(
    const float* __restrict__ w0, const float* __restrict__ w1,
    const float* __restrict__ w2, const float* __restrict__ w3,
    const float* __restrict__ w4, const float* __restrict__ w5,
    const float* __restrict__ w5c, const float* __restrict__ tw,
    unsigned short* __restrict__ wT)
{
    int y = blockIdx.y;
    unsigned short* o = wT + (size_t)y * 36864;
    if (y < 6) {
        const float* ws_[6] = {w0, w1, w2, w3, w4, w5};
        const float* w = ws_[y];
        for (int e = blockIdx.x * 256 + threadIdx.x; e < 36864; e += gridDim.x * 256) {
            int j = e & 7, oc = (e >> 3) & 63, ig = (e >> 9) & 7, tap = e >> 12;
            o[e] = f2bf(w[(oc * 64 + ig * 8 + j) * 9 + tap]);
        }
    } else if (y == 6) {
        for (int e = blockIdx.x * 256 + threadIdx.x; e < 36864; e += gridDim.x * 256)
            o[e] = f2bf(w5c[e]);
    } else {
        for (int e = blockIdx.x * 256 + threadIdx.x; e < 8192; e += gridDim.x * 256)
            o[e] = f2bf(tw[e]);
    }
}

// ---------------------------------------------------------------------------
// k_tr: NCHW fp32 -> NHWC bf16 for img and guidance (unchanged, round 5).
// ---------------------------------------------------------------------------
__global__ __launch_bounds__(256) void k_tr(
    const float* __restrict__ img, const float* __restrict__ gd,
    unsigned short* __restrict__ imgT, unsigned short* __restrict__ gdT)
{
    __shared__ float sT[64 * 66];
    int tid = threadIdx.x;
    int z = blockIdx.y;
    int b = z & 1;
    const float* src = (z >> 1) ? gd : img;
    unsigned short* dst = (z >> 1) ? gdT : imgT;
    int px0 = blockIdx.x * 64;
    size_t sbase = (size_t)b * 64 * HW + px0;

#pragma unroll
    for (int i = 0; i < 4; ++i) {
        int e = i * 256 + tid;
        int ic = e >> 4, seg = e & 15;
        float4 v = *(const float4*)(src + sbase + (size_t)ic * HW + seg * 4);
        float* p = &sT[ic * 66 + seg * 4];
        ((float2*)p)[0] = make_float2(v.x, v.y);
        ((float2*)p)[1] = make_float2(v.z, v.w);
    }
    __syncthreads();

    size_t dbase = (size_t)b * HW * 64 + (size_t)px0 * 64;
#pragma unroll
    for (int k = 0; k < 2; ++k) {
        int idx = k * 256 + tid;
        int px = idx >> 3, u = idx & 7;
        union { uint4 q; unsigned short h[8]; } o;
#pragma unroll
        for (int j = 0; j < 8; ++j)
            o.h[j] = f2bf(sT[(u * 8 + j) * 66 + px]);
        *(uint4*)(dst + dbase + (size_t)px * 64 + u * 8) = o.q;
    }
}

// ---------------------------------------------------------------------------
// k_fusem: 1x1 (2C->C) + PReLU (unchanged, round 5).
// ---------------------------------------------------------------------------
__global__ __launch_bounds__(256, 2) void k_fusem(
    const unsigned short* __restrict__ imgT, const unsigned short* __restrict__ gdT,
    const unsigned short* __restrict__ wTf, const float* __restrict__ bias,
    const float* __restrict__ a, unsigned short* __restrict__ out)
{
    __shared__ __align__(16) char smem[53504];
    uint4* sX = (uint4*)smem;
    uint4* sW = (uint4*)(smem + 36864);
    float* sB = (float*)(smem + 53248);
    unsigned short* sT16 = (unsigned short*)smem;

    int tid = threadIdx.x;
    int wv = tid >> 6, lane = tid & 63;
    int half = lane >> 5, l31 = lane & 31;
    int b = blockIdx.z;
    int y0 = blockIdx.y * 8, x0 = blockIdx.x * 32;
    size_t zbase = (size_t)b * HW * 64;

    for (int ch = tid; ch < 1024; ch += 256) {
        int kg = ch >> 6, oc = ch & 63;
        sW[ch] = ((const uint4*)wTf)[oc * 16 + kg];
    }
    if (tid < 64) sB[tid] = bias[tid];

    f32x16 acc[2][2];
#pragma unroll
    for (int i = 0; i < 2; ++i)
#pragma unroll
        for (int j = 0; j < 2; ++j)
#pragma unroll
            for (int r = 0; r < 16; ++r) acc[i][j][r] = 0.f;

    for (int h = 0; h < 2; ++h) {
        __syncthreads();
        const unsigned short* src = h ? gdT : imgT;
#pragma unroll
        for (int i = 0; i < 8; ++i) {
            int e = i * 256 + tid;
            int px = e >> 3, ig = e & 7;
            int gy = y0 + (px >> 5), gx = x0 + (px & 31);
            uint4 v = *(const uint4*)(src + zbase + ((size_t)(gy * 256 + gx)) * 64 + ig * 8);
            sX[px * 9 + ig] = v;
        }
        __syncthreads();
#pragma unroll
        for (int c = 0; c < 4; ++c) {
            int ig = c * 2 + half;
            int kg = h * 8 + ig;
            bf16x8 a0 = ld_frag(&sW[kg * 64 + l31]);
            bf16x8 a1 = ld_frag(&sW[kg * 64 + 32 + l31]);
            int p0 = wv * 64 + l31;
            bf16x8 b0 = ld_frag(&sX[p0 * 9 + ig]);
            bf16x8 b1 = ld_frag(&sX[(p0 + 32) * 9 + ig]);
            acc[0][0] = __builtin_amdgcn_mfma_f32_32x32x16_bf16(a0, b0, acc[0][0], 0, 0, 0);
            acc[0][1] = __builtin_amdgcn_mfma_f32_32x32x16_bf16(a0, b1, acc[0][1], 0, 0, 0);
            acc[1][0] = __builtin_amdgcn_mfma_f32_32x32x16_bf16(a1, b0, acc[1][0], 0, 0, 0);
            acc[1][1] = __builtin_amdgcn_mfma_f32_32x32x16_bf16(a1, b1, acc[1][1], 0, 0, 0);
        }
    }

    float slope = a[0];
    __syncthreads();
#pragma unroll
    for (int ot = 0; ot < 2; ++ot)
#pragma unroll
        for (int pt = 0; pt < 2; ++pt) {
            int px = wv * 64 + pt * 32 + l31;
#pragma unroll
            for (int q2 = 0; q2 < 4; ++q2) {
                unsigned short hw[4];
#pragma unroll
                for (int j = 0; j < 4; ++j) {
                    int r = (q2 << 2) | j;
                    int oc = ot * 32 + j + 8 * q2 + 4 * half;
                    float v = acc[ot][pt][r] + sB[oc];
                    v = (v >= 0.f) ? v : slope * v;
                    hw[j] = f2bf(v);
                }
                int unit = ot * 4 + q2;
                int up = unit ^ (px & 7);
                uint2* p = (uint2*)&sT16[px * 64 + up * 8 + half * 4];
                *p = make_uint2((unsigned)hw[0] | ((unsigned)hw[1] << 16),
                                (unsigned)hw[2] | ((unsigned)hw[3] << 16));
            }
        }
    __syncthreads();
#pragma unroll
    for (int k = 0; k < 8; ++k) {
        int col = tid >> 3, u = tid & 7;
        int px = k * 32 + col;
        uint4 v = *(uint4*)&sT16[px * 64 + (u ^ (px & 7)) * 8];
        *(uint4*)(out + zbase + ((size_t)((y0 + k) * 256 + x0 + col)) * 64 + u * 8) = v;
    }
}

// ---------------------------------------------------------------------------
// k_conv3m v3: 3x3 conv C=64->64 pad 1, bf16 MFMA, NHWC bf16 in.
// Half-channel halo in LDS (verified round-5 layout, XU=5); A-fragments
// streamed from global ([tap][ig][oc][j], coalesced, L2-hot); only 33 KB LDS
// + __launch_bounds__(256,4) -> 4 blocks/CU (2x round-5 occupancy).
// MODE 0: PReLU, NHWC bf16 out.  MODE 2: + fp32 residual, NCHW fp32 out.
// ---------------------------------------------------------------------------
#define XU 5

template<int MODE>
__global__ __launch_bounds__(256, 4) void k_conv3m(
    const unsigned short* __restrict__ in, const unsigned short* __restrict__ wT,
    const float* __restrict__ bias, const float* __restrict__ a,
    const float* __restrict__ res, void* __restrict__ outv)
{
    __shared__ __align__(16) char smem[33024];
    uint4* sX = (uint4*)smem;                     // 1620 uint4: [cell][ig_l 0..3 +pad]
    float* sB = (float*)(smem + 32768);           // 64 f32 (outside the overlay!)
    unsigned short* sT16 = (unsigned short*)smem; // epilogue overlay 32KB (MODE 0)

    int tid = threadIdx.x;
    int wv = tid >> 6, lane = tid & 63;
    int half = lane >> 5, l31 = lane & 31;
    int b = blockIdx.z;
    int y0 = blockIdx.y * 16, x0 = blockIdx.x * 16;
    const size_t zbase = (size_t)b * HW * 64;

    if (tid < 64) sB[tid] = bias[tid];

    f32x16 acc[2][2];
#pragma unroll
    for (int i = 0; i < 2; ++i)
#pragma unroll
        for (int j = 0; j < 2; ++j)
#pragma unroll
            for (int r = 0; r < 16; ++r) acc[i][j][r] = 0.f;

    const uint4* wq = (const uint4*)wT;

    for (int h = 0; h < 2; ++h) {
        __syncthreads();
        // stage halo for this ic-half: 18x18 cells x 4 uint4 (32 ch)
#pragma unroll
        for (int i = 0; i < 6; ++i) {
            int e = i * 256 + tid;
            if (e < 1296) {
                int cell = e >> 2, ig = e & 3;
                int r = cell / 18, c = cell - r * 18;
                int gy = y0 + r - 1, gx = x0 + c - 1;
                uint4 v = make_uint4(0, 0, 0, 0);
                if (gy >= 0 && gy < 256 && gx >= 0 && gx < 256)
                    v = *(const uint4*)(in + zbase + ((size_t)(gy * 256 + gx)) * 64 + h * 32 + ig * 8);
                sX[cell * XU + ig] = v;
            }
        }
        __syncthreads();

#pragma unroll
        for (int tap = 0; tap < 9; ++tap) {
            int dy = tap / 3, dx = tap % 3;
#pragma unroll
            for (int c = 0; c < 2; ++c) {
                int ig = c * 2 + half;                // local k-group in half
                int igg = h * 4 + ig;                 // global ic-group
                bf16x8 a0 = ld_frag(&wq[(tap * 8 + igg) * 64 + l31]);
                bf16x8 a1 = ld_frag(&wq[(tap * 8 + igg) * 64 + 32 + l31]);
                int p0 = wv * 64 + l31;
                int p1 = p0 + 32;
                int u0 = ((((p0 >> 4) + dy) * 18) + (p0 & 15) + dx) * XU + ig;
                int u1 = ((((p1 >> 4) + dy) * 18) + (p1 & 15) + dx) * XU + ig;
                bf16x8 b0 = ld_frag(&sX[u0]);
                bf16x8 b1 = ld_frag(&sX[u1]);
                acc[0][0] = __builtin_amdgcn_mfma_f32_32x32x16_bf16(a0, b0, acc[0][0], 0, 0, 0);
                acc[0][1] = __builtin_amdgcn_mfma_f32_32x32x16_bf16(a0, b1, acc[0][1], 0, 0, 0);
                acc[1][0] = __builtin_amdgcn_mfma_f32_32x32x16_bf16(a1, b0, acc[1][0], 0, 0, 0);
                acc[1][1] = __builtin_amdgcn_mfma_f32_32x32x16_bf16(a1, b1, acc[1][1], 0, 0, 0);
            }
        }
    }

    if (MODE == 0) {
        float slope = a[0];
        __syncthreads();
#pragma unroll
        for (int ot = 0; ot < 2; ++ot)
#pragma unroll
            for (int pt = 0; pt < 2; ++pt) {
                int px = wv * 64 + pt * 32 + l31;
#pragma unroll
                for (int q2 = 0; q2 < 4; ++q2) {
                    unsigned short hw[4];
#pragma unroll
                    for (int j = 0; j < 4; ++j) {
                        int r = (q2 << 2) | j;
                        int oc = ot * 32 + j + 8 * q2 + 4 * half;
                        float v = acc[ot][pt][r] + sB[oc];
                        v = (v >= 0.f) ? v : slope * v;
                        hw[j] = f2bf(v);
                    }
                    int unit = ot * 4 + q2;
                    int up = unit ^ (px & 7);
                    uint2* p = (uint2*)&sT16[px * 64 + up * 8 + half * 4];
                    *p = make_uint2((unsigned)hw[0] | ((unsigned)hw[1] << 16),
                                    (unsigned)hw[2] | ((unsigned)hw[3] << 16));
                }
            }
        __syncthreads();
        unsigned short* outT = (unsigned short*)outv;
#pragma unroll
        for (int k = 0; k < 8; ++k) {
            int idx = k * 256 + tid;
            int row = idx >> 7, rem = idx & 127;
            int col = rem >> 3, u = rem & 7;
            int px = row * 16 + col;
            uint4 v = *(uint4*)&sT16[px * 64 + (u ^ (px & 7)) * 8];
            *(uint4*)(outT + zbase + ((size_t)((y0 + row) * 256 + x0 + col)) * 64 + u * 8) = v;
        }
    } else {
        float* outF = (float*)outv;
#pragma unroll
        for (int ot = 0; ot < 2; ++ot)
#pragma unroll
            for (int pt = 0; pt < 2; ++pt) {
                int p = wv * 64 + pt * 32 + l31;
                int y = y0 + (p >> 4), x = x0 + (p & 15);
                size_t pbase = (size_t)b * 64 * HW + (size_t)y * 256 + x;
#pragma unroll
                for (int r = 0; r < 16; ++r) {
                    int oc = ot * 32 + (r & 3) + 8 * (r >> 2) + 4 * half;
                    float v = acc[ot][pt][r] + sB[oc];
                    v += res[pbase + (size_t)oc * HW];
                    outF[pbase + (size_t)oc * HW] = v;
                }
            }
    }
}

// ---------------------------------------------------------------------------
// k_jbfm: fused kg_w5 (C->576) + dynamic-kernel combine.
// EXACT round-5 version (59 us verified; no register prefetch -> no spill).
// ---------------------------------------------------------------------------
__global__ __launch_bounds__(256, 2) void k_jbfm(
    const unsigned short* __restrict__ y4, const float* __restrict__ img,
    const unsigned short* __restrict__ w5T, const float* __restrict__ b5,
    unsigned short* __restrict__ out)
{
    __shared__ __align__(16) char smem[58880];
    uint4* sY  = (uint4*)smem;                   // 2304 uint4: [px][ig 0..8(pad)]
    uint4* sW5 = (uint4*)(smem + 36864);         // 512 uint4: [ig][cc]
    unsigned* sP = (unsigned*)(smem + 45056);    // 2880 u32: [ch8][rp9][col40]
    float* sB5 = (float*)(smem + 56576);         // 576 f32
    unsigned short* sT16 = (unsigned short*)smem;

    int tid = threadIdx.x;
    int wv = tid >> 6, lane = tid & 63;
    int half = lane >> 5, l31 = lane & 31;
    int b = blockIdx.z;
    int y0 = blockIdx.y * 8, x0 = blockIdx.x * 32;
    size_t zbase = (size_t)b * HW * 64;
    size_t ibase = (size_t)b * 64 * HW;

#pragma unroll
    for (int i = 0; i < 8; ++i) {
        int e = i * 256 + tid;
        int px = e >> 3, ig = e & 7;
        int gy = y0 + (px >> 5), gx = x0 + (px & 31);
        sY[px * 9 + ig] = *(const uint4*)(y4 + zbase + ((size_t)(gy * 256 + gx)) * 64 + ig * 8);
    }
    for (int e = tid; e < 576; e += 256) sB5[e] = b5[e];

    float jb[2][2][16];
#pragma unroll
    for (int i = 0; i < 2; ++i)
#pragma unroll
        for (int j = 0; j < 2; ++j)
#pragma unroll
            for (int r = 0; r < 16; ++r) jb[i][j][r] = 0.f;

#pragma unroll
    for (int kk = 0; kk < 9; ++kk) {
        const int chlo = (kk * 64) / 9;
        __syncthreads();
        for (int u = tid; u < 512; u += 256) {
            int cc = u & 63, ig = u >> 6;
            sW5[u] = ((const uint4*)w5T)[(kk * 64 + cc) * 8 + ig];
        }
#pragma unroll
        for (int i = 0; i < 3; ++i) {
            int e = i * 256 + tid;
            if (e < 720) {
                int ch = e / 90, rem = e - ch * 90;
                int rp = rem / 10, seg = rem - rp * 10;
                int gy = y0 + rp - 1;
                int gxb = x0 - 4 + seg * 4;
                bool xok = (gxb >= 0 && gxb < 256);
                float4 fa = make_float4(0, 0, 0, 0), fb = make_float4(0, 0, 0, 0);
                const float* rowp = img + ibase + (size_t)(chlo + ch) * HW + gxb;
                if (xok && gy >= 0 && gy < 256)         fa = *(const float4*)(rowp + (size_t)gy * 256);
                if (xok && gy + 1 >= 0 && gy + 1 < 256) fb = *(const float4*)(rowp + (size_t)(gy + 1) * 256);
                uint4 pk;
                pk.x = (unsigned)f2bf(fa.x) | ((unsigned)f2bf(fb.x) << 16);
                pk.y = (unsigned)f2bf(fa.y) | ((unsigned)f2bf(fb.y) << 16);
                pk.z = (unsigned)f2bf(fa.z) | ((unsigned)f2bf(fb.z) << 16);
                pk.w = (unsigned)f2bf(fa.w) | ((unsigned)f2bf(fb.w) << 16);
                *(uint4*)&sP[ch * 360 + rp * 40 + seg * 4] = pk;
            }
        }
        __syncthreads();

        f32x16 acc[2][2];
#pragma unroll
        for (int ot = 0; ot < 2; ++ot)
#pragma unroll
            for (int r = 0; r < 16; ++r) {
                int cc0 = ot * 32 + (r & 3) + 8 * (r >> 2);
                float bv = sB5[kk * 64 + cc0 + 4 * half];
                acc[ot][0][r] = bv;
                acc[ot][1][r] = bv;
            }

#pragma unroll
        for (int c = 0; c < 4; ++c) {
            int ig = c * 2 + half;
            bf16x8 a0 = ld_frag(&sW5[ig * 64 + l31]);
            bf16x8 a1 = ld_frag(&sW5[ig * 64 + 32 + l31]);
            int p0 = wv * 64 + l31;
            bf16x8 b0 = ld_frag(&sY[p0 * 9 + ig]);
            bf16x8 b1 = ld_frag(&sY[(p0 + 32) * 9 + ig]);
            acc[0][0] = __builtin_amdgcn_mfma_f32_32x32x16_bf16(a0, b0, acc[0][0], 0, 0, 0);
            acc[0][1] = __builtin_amdgcn_mfma_f32_32x32x16_bf16(a0, b1, acc[0][1], 0, 0, 0);
            acc[1][0] = __builtin_amdgcn_mfma_f32_32x32x16_bf16(a1, b0, acc[1][0], 0, 0, 0);
            acc[1][1] = __builtin_amdgcn_mfma_f32_32x32x16_bf16(a1, b1, acc[1][1], 0, 0, 0);
        }

        {
            const unsigned* basep = sP + wv * 80 + l31 + 3;
#pragma unroll
            for (int ot = 0; ot < 2; ++ot)
#pragma unroll
                for (int r = 0; r < 16; ++r) {
                    const int cc0 = ot * 32 + (r & 3) + 8 * (r >> 2);
                    const int q0 = kk * 64 + cc0, q1 = q0 + 4;
                    const int o0 = (q0 / 9 - chlo) * 360 + (q0 % 9 / 3) * 40 + q0 % 9 % 3;
                    const int o1 = (q1 / 9 - chlo) * 360 + (q1 % 9 / 3) * 40 + q1 % 9 % 3;
                    unsigned pv = basep[half ? o1 : o0];
                    jb[ot][0][r] = fmaf(acc[ot][0][r], bflo2f(pv), jb[ot][0][r]);
                    jb[ot][1][r] = fmaf(acc[ot][1][r], bfhi2f(pv), jb[ot][1][r]);
                }
        }
    }

    __syncthreads();
#pragma unroll
    for (int ot = 0; ot < 2; ++ot)
#pragma unroll
        for (int pt = 0; pt < 2; ++pt) {
            int px = wv * 64 + pt * 32 + l31;
#pragma unroll
            for (int q2 = 0; q2 < 4; ++q2) {
                unsigned short hw[4];
#pragma unroll
                for (int j = 0; j < 4; ++j) {
                    int r = (q2 << 2) | j;
                    hw[j] = f2bf(jb[ot][pt][r]);
                }
                int unit = ot * 4 + q2;
                int up = unit ^ (px & 7);
                uint2* p = (uint2*)&sT16[px * 64 + up * 8 + half * 4];
                *p = make_uint2((unsigned)hw[0] | ((unsigned)hw[1] << 16),
                                (unsigned)hw[2] | ((unsigned)hw[3] << 16));
            }
        }
    __syncthreads();
#pragma unroll
    for (int k = 0; k < 8; ++k) {
        int col = tid >> 3, u = tid & 7;
        int px = k * 32 + col;
        uint4 v = *(uint4*)&sT16[px * 64 + (u ^ (px & 7)) * 8];
        *(uint4*)(out + zbase + ((size_t)((y0 + k) * 256 + x0 + col)) * 64 + u * 8) = v;
    }
}

// ---------------------------------------------------------------------------
extern "C" void kernel_launch(void* const* d_in, const int* in_sizes, int n_in,
                              void* d_out, int out_size, void* d_ws, size_t ws_size,
                              hipStream_t stream) {
    const float* img  = (const float*)d_in[0];
    const float* gd   = (const float*)d_in[1];
    const float* tw   = (const float*)d_in[2];
    const float* tb   = (const float*)d_in[3];
    const float* ajbf = (const float*)d_in[4];
    const float* kw1  = (const float*)d_in[5];
    const float* kb1  = (const float*)d_in[6];
    const float* kw2  = (const float*)d_in[7];
    const float* kb2  = (const float*)d_in[8];
    const float* kw3  = (const float*)d_in[9];
    const float* kb3  = (const float*)d_in[10];
    const float* kw4  = (const float*)d_in[11];
    const float* kb4  = (const float*)d_in[12];
    const float* kw5  = (const float*)d_in[13];
    const float* kb5  = (const float*)d_in[14];
    const float* akg  = (const float*)d_in[15];
    const float* jw1  = (const float*)d_in[16];
    const float* jb1  = (const float*)d_in[17];
    const float* jw2  = (const float*)d_in[18];
    const float* jb2  = (const float*)d_in[19];
    float* out  = (float*)d_out;

    const size_t TEN = (size_t)2 * HW * 64;
    unsigned short* bufA = (unsigned short*)d_ws;
    unsigned short* imgT = bufA + TEN;
    unsigned short* gdT  = imgT + TEN;
    unsigned short* wT   = gdT + TEN;
    unsigned short* bufB = (unsigned short*)d_out;

    dim3 g3(16, 16, 2);
    dim3 gw(8, 32, 2);

    k_tr<<<dim3(1024, 4), 256, 0, stream>>>(img, gd, imgT, gdT);
    k_wprep<<<dim3(4, 8), 256, 0, stream>>>(kw1, kw2, kw3, kw4, jw1, jw2, kw5, tw, wT);

    k_fusem<<<gw, 256, 0, stream>>>(imgT, gdT, wT + (size_t)7 * 36864, tb, ajbf, bufA);

    k_conv3m<0><<<g3, 256, 0, stream>>>(bufA, wT + (size_t)0 * 36864, kb1, akg, nullptr, bufB);
    k_conv3m<0><<<g3, 256, 0, stream>>>(bufB, wT + (size_t)1 * 36864, kb2, akg, nullptr, bufA);
    k_conv3m<0><<<g3, 256, 0, stream>>>(bufA, wT + (size_t)2 * 36864, kb3, akg, nullptr, bufB);
    k_conv3m<0><<<g3, 256, 0, stream>>>(bufB, wT + (size_t)3 * 36864, kb4, akg, nullptr, bufA);

    k_jbfm<<<gw, 256, 0, stream>>>(bufA, img, wT + (size_t)6 * 36864, kb5, bufB);

    k_conv3m<0><<<g3, 256, 0, stream>>>(bufB, wT + (size_t)4 * 36864, jb1, ajbf, nullptr, bufA);
    k_conv3m<2><<<g3, 256, 0, stream>>>(bufA, wT + (size_t)5 * 36864, jb2, ajbf, img, out);
}